// Round 11
// baseline (1135.211 us; speedup 1.0000x reference)
//
#include <hip/hip_runtime.h>
#include <hip/hip_bf16.h>
#include <hip/hip_fp16.h>

#define Vn 10000
#define En 300
#define E2n 150   // En/2 f16 pairs
#define Hn 256
#define Gn 1024   // 4*H
#define Ln 9
#define Bn 128
#define Tn 512

#if defined(__has_builtin)
#  if __has_builtin(__builtin_amdgcn_sdot8)
#    define HAS_SDOT8 1
#  endif
#  if __has_builtin(__builtin_amdgcn_fdot2)
#    define HAS_FDOT2 1
#  endif
#endif
#ifndef HAS_SDOT8
#  define HAS_SDOT8 0
#endif
#ifndef HAS_FDOT2
#  define HAS_FDOT2 0
#endif

typedef _Float16 half2_t __attribute__((ext_vector_type(2)));

static __device__ __forceinline__ float bf2f(unsigned short u) {
    return __uint_as_float(((unsigned int)u) << 16);
}
static __device__ __forceinline__ unsigned short f2bf(float f) {
    unsigned int x = __float_as_uint(f);
    return (unsigned short)((x + 0x7FFFu + ((x >> 16) & 1u)) >> 16);
}
static __device__ __forceinline__ float sigm(float x) {
    return 1.f / (1.f + __expf(-x));
}
static __device__ __forceinline__ float tanh_fast(float x) {
    return 2.f / (1.f + __expf(-2.f * x)) - 1.f;
}
// i4x8 dot: both operands are 8 packed signed nibbles
static __device__ __forceinline__ int dot8(unsigned int w, int h, int acc) {
#if HAS_SDOT8
    return __builtin_amdgcn_sdot8((int)w, h, acc, false);
#else
    unsigned int wl = ((w & 0x0F0F0F0Fu) ^ 0x08080808u) - 0x08080808u;
    unsigned int wh = (((w >> 4) & 0x0F0F0F0Fu) ^ 0x08080808u) - 0x08080808u;
    unsigned int hl = (((unsigned)h & 0x0F0F0F0Fu) ^ 0x08080808u) - 0x08080808u;
    unsigned int hh = ((((unsigned)h >> 4) & 0x0F0F0F0Fu) ^ 0x08080808u) - 0x08080808u;
    acc = __builtin_amdgcn_sdot4((int)wl, (int)hl, acc, false);
    return __builtin_amdgcn_sdot4((int)wh, (int)hh, acc, false);
#endif
}
static __device__ __forceinline__ float fdot2f(unsigned int a, unsigned int b, float acc) {
#if HAS_FDOT2
    return __builtin_amdgcn_fdot2(__builtin_bit_cast(half2_t, a),
                                  __builtin_bit_cast(half2_t, b), acc, false);
#else
    half2_t av = __builtin_bit_cast(half2_t, a);
    half2_t bv = __builtin_bit_cast(half2_t, b);
    return acc + (float)av.x * (float)bv.x + (float)av.y * (float)bv.y;
#endif
}
static __device__ __forceinline__ unsigned int packf16(float a, float b) {
    half2_t v = {(_Float16)a, (_Float16)b};
    return __builtin_bit_cast(unsigned int, v);
}

// ---- pack emb (10000,300) f32 -> f16-pair dwords [v][e2] ----
__global__ __launch_bounds__(256) void k_prep_emb(
    const float* __restrict__ emb, unsigned int* __restrict__ embp) {
    int n = blockIdx.x * 256 + threadIdx.x;
    if (n >= Vn * E2n) return;
    int v = n / E2n, e2 = n % E2n;
    float a = emb[(size_t)v * En + 2 * e2];
    float b = emb[(size_t)v * En + 2 * e2 + 1];
    embp[n] = packf16(a, b);
}

// ---- pack+transpose Wih (1024,300) -> WT16 [e2][j] f16-pair dwords ----
__global__ __launch_bounds__(256) void k_prep_wt(
    const float* __restrict__ Wf, const float* __restrict__ Wb,
    unsigned int* __restrict__ Tf, unsigned int* __restrict__ Tb) {
    int n = blockIdx.x * 256 + threadIdx.x;           // < 153600
    const float* src = blockIdx.y ? Wb : Wf;
    unsigned int* dst = blockIdx.y ? Tb : Tf;
    int e2 = n / Gn, j = n % Gn;
    float a = src[(size_t)j * En + 2 * e2];
    float b = src[(size_t)j * En + 2 * e2 + 1];
    dst[n] = packf16(a, b);
}

// ---- quantize Whh (1024,256) f32 -> i4 nibbles, per-gate-row scale ----
// Quad layout for k_lstm thread tid = 4*u + kq (u=unit, kq=k-quarter):
//  row j = u + 256*g, dword e = 8*kq + 4*half + sub (k = 8e..8e+7).
//  gates 0..2 -> qr tile (g*2+half): qr[(g*2+half)*1024 + tid][sub]
//  gate 3     -> ql tile half:       ql[half*1024 + tid][sub]
// gate = scl[j]*dotsum + P, scl = rowmax/49 (w,h in [-7,7]).
__global__ __launch_bounds__(64) void k_quant_whh(
    const float* __restrict__ Wf, const float* __restrict__ Wb,
    unsigned int* __restrict__ qr_f, unsigned int* __restrict__ ql_f,
    unsigned int* __restrict__ qr_b, unsigned int* __restrict__ ql_b,
    float* __restrict__ scl_f, float* __restrict__ scl_b) {
    int j = blockIdx.x;                 // 0..1023 (gate-row)
    int dir = blockIdx.y;
    int lane = threadIdx.x;             // lanes 0..31 = dword index e
    const float* W = dir ? Wb : Wf;
    float w8[8];
    float m = 0.f;
    if (lane < 32) {
        float4 wlo = *(const float4*)&W[(size_t)j * Hn + 8 * lane];
        float4 whi = *(const float4*)&W[(size_t)j * Hn + 8 * lane + 4];
        w8[0] = wlo.x; w8[1] = wlo.y; w8[2] = wlo.z; w8[3] = wlo.w;
        w8[4] = whi.x; w8[5] = whi.y; w8[6] = whi.z; w8[7] = whi.w;
        #pragma unroll
        for (int i = 0; i < 8; ++i) m = fmaxf(m, fabsf(w8[i]));
    }
    #pragma unroll
    for (int sft = 32; sft >= 1; sft >>= 1) m = fmaxf(m, __shfl_xor(m, sft, 64));
    float inv = (m > 0.f) ? (7.f / m) : 0.f;
    if (lane < 32) {
        unsigned int d = 0;
        #pragma unroll
        for (int i = 0; i < 8; ++i) {
            int qi = (int)rintf(w8[i] * inv);
            d |= ((unsigned int)(qi & 0xF)) << (4 * i);
        }
        int u = j & 255, g = j >> 8;
        int kq = lane >> 3, half = (lane >> 2) & 1, sub = lane & 3;
        int tid = 4 * u + kq;
        if (g < 3)
            (dir ? qr_b : qr_f)[(size_t)((g * 2 + half) * 1024 + tid) * 4 + sub] = d;
        else
            (dir ? ql_b : ql_f)[(size_t)(half * 1024 + tid) * 4 + sub] = d;
    }
    if (lane == 0) (dir ? scl_b : scl_f)[j] = m / 49.f;
}

// ---- P = emb @ WihT + b via v_dot2_f32_f16 : (10000, 1024) bf16 per dir ----
__global__ __launch_bounds__(256) void k_proj(
    const unsigned int* __restrict__ embp,
    const unsigned int* __restrict__ WT16_f, const unsigned int* __restrict__ WT16_b,
    const float* __restrict__ b_f, const float* __restrict__ b_b,
    unsigned short* __restrict__ Pf, unsigned short* __restrict__ Pb) {
    int tid = threadIdx.x;
    int tx = tid & 63, ty = tid >> 6;
    int dir = blockIdx.z;
    const unsigned int* WT = dir ? WT16_b : WT16_f;
    const float* bias = dir ? b_b : b_f;
    unsigned short* P = dir ? Pb : Pf;
    int v0 = blockIdx.x * 32 + ty * 8;               // 313 blocks, tail-guarded
    int j0 = blockIdx.y * 256 + tx * 4;
    int vr[8];
    #pragma unroll
    for (int r = 0; r < 8; ++r) { int v = v0 + r; vr[r] = (v < Vn) ? v : Vn - 1; }
    float4 acc[8];
    #pragma unroll
    for (int r = 0; r < 8; ++r) acc[r] = make_float4(0.f, 0.f, 0.f, 0.f);
    for (int e2 = 0; e2 < E2n; e2 += 2) {            // 150 even
        uint4 w0 = *(const uint4*)&WT[(size_t)(e2 + 0) * Gn + j0];
        uint4 w1 = *(const uint4*)&WT[(size_t)(e2 + 1) * Gn + j0];
        #pragma unroll
        for (int r = 0; r < 8; ++r) {
            uint2 a = *(const uint2*)&embp[(size_t)vr[r] * E2n + e2];
            acc[r].x = fdot2f(a.x, w0.x, acc[r].x);
            acc[r].y = fdot2f(a.x, w0.y, acc[r].y);
            acc[r].z = fdot2f(a.x, w0.z, acc[r].z);
            acc[r].w = fdot2f(a.x, w0.w, acc[r].w);
            acc[r].x = fdot2f(a.y, w1.x, acc[r].x);
            acc[r].y = fdot2f(a.y, w1.y, acc[r].y);
            acc[r].z = fdot2f(a.y, w1.z, acc[r].z);
            acc[r].w = fdot2f(a.y, w1.w, acc[r].w);
        }
    }
    float4 bb = *(const float4*)&bias[j0];
    #pragma unroll
    for (int r = 0; r < 8; ++r) {
        if (v0 + r < Vn) {
            ushort4 o;
            o.x = f2bf(acc[r].x + bb.x); o.y = f2bf(acc[r].y + bb.y);
            o.z = f2bf(acc[r].z + bb.z); o.w = f2bf(acc[r].w + bb.w);
            *(ushort4*)&P[(size_t)(v0 + r) * Gn + j0] = o;
        }
    }
}

// ---- persistent BiLSTM recurrence: 256 WGs = 2 dir x 128 batch, 1024 thr ----
// QUAD LAYOUT: thread tid = 4*u + kq computes ALL 4 gates' kq-quarter dots for
// unit u. h arrives as per-lane ds_read_b128 used directly by sdot8 (zero
// readlanes). Gate totals via intra-quad shfl_xor butterflies (DPP). Epilogue
// on kq==0 lanes of EVERY wave. h4v double-buffered -> ONE barrier/step.
// Weights: 24 dwords pinned (gates i,f,g) + 8 in LDS (gate o).
__global__ __launch_bounds__(1024, 4) void k_lstm(
    const int* __restrict__ ids,
    const uint4* __restrict__ qr_f, const uint4* __restrict__ ql_f,
    const uint4* __restrict__ qr_b, const uint4* __restrict__ ql_b,
    const float* __restrict__ scl_f, const float* __restrict__ scl_b,
    const unsigned short* __restrict__ Pf, const unsigned short* __restrict__ Pb,
    unsigned short* __restrict__ hs_f, unsigned short* __restrict__ hs_b) {
    __shared__ uint4 wlds[2 * 1024];          // 32 KB gate-o weights
    __shared__ unsigned int h4q[2][32];       // 2 x 128 B double-buffered i4 h
    __shared__ int ids_lds[Tn];               // 2 KB
    int tid = threadIdx.x;
    int dir = blockIdx.x >> 7;
    int batch = blockIdx.x & 127;
    int u = tid >> 2, kq = tid & 3;
    const uint4* qr = dir ? qr_b : qr_f;
    const uint4* ql = dir ? ql_b : ql_f;
    const unsigned short* P = dir ? Pb : Pf;
    unsigned short* hs = dir ? hs_b : hs_f;

    unsigned int wReg[24];
    #pragma unroll
    for (int d6 = 0; d6 < 6; ++d6) {
        uint4 v = qr[(size_t)d6 * 1024 + tid];
        wReg[4*d6+0] = v.x; wReg[4*d6+1] = v.y; wReg[4*d6+2] = v.z; wReg[4*d6+3] = v.w;
    }
    wlds[tid] = ql[tid];
    wlds[1024 + tid] = ql[1024 + tid];
    // scl gather: lane loads gate-kq's scale; kq0 collects all 4 via quad shfl
    float myscl = (dir ? scl_b : scl_f)[u + 256 * kq];
    float sc0 = myscl;
    float sc1 = __shfl_xor(myscl, 1, 64);
    float sc2 = __shfl_xor(myscl, 2, 64);
    float sc3 = __shfl_xor(myscl, 3, 64);
    if (tid < Tn) ids_lds[tid] = ids[batch * Tn + tid];
    if (tid < 32) h4q[0][tid] = 0u;
    float c = 0.f;
    __syncthreads();

    int t0 = dir ? (Tn - 1) : 0;
    unsigned short pcur = P[(size_t)ids_lds[t0] * Gn + u + 256 * kq];

    for (int s = 0; s < Tn; ++s) {
        // loop-carried pin: wReg must stay live in the register file
        asm volatile("" : "+v"(wReg[0]), "+v"(wReg[1]), "+v"(wReg[2]), "+v"(wReg[3]),
                          "+v"(wReg[4]), "+v"(wReg[5]), "+v"(wReg[6]), "+v"(wReg[7]),
                          "+v"(wReg[8]), "+v"(wReg[9]), "+v"(wReg[10]), "+v"(wReg[11]));
        asm volatile("" : "+v"(wReg[12]), "+v"(wReg[13]), "+v"(wReg[14]), "+v"(wReg[15]),
                          "+v"(wReg[16]), "+v"(wReg[17]), "+v"(wReg[18]), "+v"(wReg[19]),
                          "+v"(wReg[20]), "+v"(wReg[21]), "+v"(wReg[22]), "+v"(wReg[23]));

        int t = dir ? (Tn - 1 - s) : s;
        int cur = s & 1;
        int s2 = (s + 1 < Tn) ? s + 1 : Tn - 1;
        int t2 = dir ? (Tn - 1 - s2) : s2;
        unsigned short pnx = P[(size_t)ids_lds[t2] * Gn + u + 256 * kq]; // prefetch

        const uint4* hb = (const uint4*)&h4q[cur][kq * 8];
        uint4 h0 = hb[0], h1 = hb[1];             // 2 ds_read_b128, per-lane
        uint4 wo0 = wlds[tid], wo1 = wlds[1024 + tid];

        int a0 = 0, a1 = 0, a2 = 0, a3 = 0;       // gates i,f,g,o (kq-quarter)
        a0 = dot8(wReg[0], (int)h0.x, a0);  a0 = dot8(wReg[1], (int)h0.y, a0);
        a0 = dot8(wReg[2], (int)h0.z, a0);  a0 = dot8(wReg[3], (int)h0.w, a0);
        a0 = dot8(wReg[4], (int)h1.x, a0);  a0 = dot8(wReg[5], (int)h1.y, a0);
        a0 = dot8(wReg[6], (int)h1.z, a0);  a0 = dot8(wReg[7], (int)h1.w, a0);
        a1 = dot8(wReg[8], (int)h0.x, a1);  a1 = dot8(wReg[9], (int)h0.y, a1);
        a1 = dot8(wReg[10], (int)h0.z, a1); a1 = dot8(wReg[11], (int)h0.w, a1);
        a1 = dot8(wReg[12], (int)h1.x, a1); a1 = dot8(wReg[13], (int)h1.y, a1);
        a1 = dot8(wReg[14], (int)h1.z, a1); a1 = dot8(wReg[15], (int)h1.w, a1);
        a2 = dot8(wReg[16], (int)h0.x, a2); a2 = dot8(wReg[17], (int)h0.y, a2);
        a2 = dot8(wReg[18], (int)h0.z, a2); a2 = dot8(wReg[19], (int)h0.w, a2);
        a2 = dot8(wReg[20], (int)h1.x, a2); a2 = dot8(wReg[21], (int)h1.y, a2);
        a2 = dot8(wReg[22], (int)h1.z, a2); a2 = dot8(wReg[23], (int)h1.w, a2);
        a3 = dot8(wo0.x, (int)h0.x, a3);    a3 = dot8(wo0.y, (int)h0.y, a3);
        a3 = dot8(wo0.z, (int)h0.z, a3);    a3 = dot8(wo0.w, (int)h0.w, a3);
        a3 = dot8(wo1.x, (int)h1.x, a3);    a3 = dot8(wo1.y, (int)h1.y, a3);
        a3 = dot8(wo1.z, (int)h1.z, a3);    a3 = dot8(wo1.w, (int)h1.w, a3);

        // intra-quad butterfly: full gate sums land in every quad lane
        a0 += __shfl_xor(a0, 1, 64); a0 += __shfl_xor(a0, 2, 64);
        a1 += __shfl_xor(a1, 1, 64); a1 += __shfl_xor(a1, 2, 64);
        a2 += __shfl_xor(a2, 1, 64); a2 += __shfl_xor(a2, 2, 64);
        a3 += __shfl_xor(a3, 1, 64); a3 += __shfl_xor(a3, 2, 64);

        // P gather: lane kq holds P for gate kq; kq0 collects all 4
        float pv = bf2f(pcur);
        float p1 = __shfl_xor(pv, 1, 64);
        float p2 = __shfl_xor(pv, 2, 64);
        float p3 = __shfl_xor(pv, 3, 64);

        int qh = 0;
        if (kq == 0) {
            float gi = sc0 * (float)a0 + pv;
            float gf = sc1 * (float)a1 + p1;
            float gg = sc2 * (float)a2 + p2;
            float go = sc3 * (float)a3 + p3;
            float cn = sigm(gf) * c + sigm(gi) * tanh_fast(gg);
            float hn = sigm(go) * tanh_fast(cn);
            c = cn;
            hs[(size_t)(t * Bn + batch) * Hn + u] = f2bf(hn);
            qh = (int)rintf(7.f * hn) & 0xF;
        }
        // nibble pack: units u,u+1 -> byte (xor4), +2 -> u16 (xor8), +4 -> u32 (xor16)
        int o1 = __shfl_xor(qh, 4, 64);
        int b8 = qh | (o1 << 4);
        int o2 = __shfl_xor(b8, 8, 64);
        int b16 = (b8 & 0xFF) | ((o2 & 0xFF) << 8);
        int o3 = __shfl_xor(b16, 16, 64);
        unsigned int b32 = (unsigned int)((b16 & 0xFFFF) | (o3 << 16));
        if ((tid & 31) == 0) h4q[cur ^ 1][tid >> 5] = b32;
        __syncthreads();                          // ONE barrier per step
        pcur = pnx;
    }
}

// ---- emissions: em[t,b,l] = [hf|hb].Wc[l] + bc[l], one wave per token ----
__global__ __launch_bounds__(256) void k_emit(
    const unsigned short* __restrict__ hs_f, const unsigned short* __restrict__ hs_b,
    const float* __restrict__ Wc, const float* __restrict__ bc,
    float* __restrict__ em) {
    __shared__ float wc_s[Ln * 2 * Hn];
    int tid = threadIdx.x;
    for (int i = tid; i < Ln * 2 * Hn; i += 256) wc_s[i] = Wc[i];
    __syncthreads();
    int lane = tid & 63, wid = tid >> 6;
    int tb = blockIdx.x * 4 + wid;                   // t*128 + b, < 65536
    const unsigned short* hf = hs_f + (size_t)tb * Hn;
    const unsigned short* hb = hs_b + (size_t)tb * Hn;
    uint2 uf = *(const uint2*)&hf[lane * 4];
    uint2 ub = *(const uint2*)&hb[lane * 4];
    float f0 = __uint_as_float(uf.x << 16), f1 = __uint_as_float(uf.x & 0xFFFF0000u);
    float f2v = __uint_as_float(uf.y << 16), f3 = __uint_as_float(uf.y & 0xFFFF0000u);
    float b0 = __uint_as_float(ub.x << 16), b1 = __uint_as_float(ub.x & 0xFFFF0000u);
    float b2 = __uint_as_float(ub.y << 16), b3 = __uint_as_float(ub.y & 0xFFFF0000u);
    #pragma unroll
    for (int l = 0; l < Ln; ++l) {
        const float* w = &wc_s[l * 2 * Hn];
        float p = f0 * w[4 * lane] + f1 * w[4 * lane + 1]
                + f2v * w[4 * lane + 2] + f3 * w[4 * lane + 3]
                + b0 * w[Hn + 4 * lane] + b1 * w[Hn + 4 * lane + 1]
                + b2 * w[Hn + 4 * lane + 2] + b3 * w[Hn + 4 * lane + 3];
        #pragma unroll
        for (int m = 32; m >= 1; m >>= 1) p += __shfl_xor(p, m, 64);
        if (lane == 0) em[(size_t)tb * Ln + l] = p + bc[l];
    }
}

// ---- CRF denominator: 64 single-wave WGs, 2 batches/wave, shuffle-based ----
__global__ __launch_bounds__(64) void k_crf_den(
    const float* __restrict__ em, const int* __restrict__ mask,
    const float* __restrict__ trans, const float* __restrict__ start,
    const float* __restrict__ endt, float* __restrict__ logZ) {
    int lane = threadIdx.x;
    int grp = lane >> 5;                             // 0 or 1
    int b = blockIdx.x + 64 * grp;
    int lj = lane & 31;
    int jj = (lj < Ln) ? lj : Ln - 1;                // clamp for safe loads
    int base = lane & 32;                            // shfl source base
    float trj[Ln];
    #pragma unroll
    for (int i = 0; i < Ln; ++i) trj[i] = trans[i * Ln + jj];
    float alpha = start[jj] + em[(size_t)b * Ln + jj];
    float e1 = em[(size_t)(1 * Bn + b) * Ln + jj];
    float e2 = em[(size_t)(2 * Bn + b) * Ln + jj];
    int m1 = mask[b * Tn + 1];
    int m2 = mask[b * Tn + 2];
    for (int t = 1; t < Tn; ++t) {
        float s0 = __shfl(alpha, base + 0, 64) + trj[0];
        float s1 = __shfl(alpha, base + 1, 64) + trj[1];
        float s2 = __shfl(alpha, base + 2, 64) + trj[2];
        float s3 = __shfl(alpha, base + 3, 64) + trj[3];
        float s4 = __shfl(alpha, base + 4, 64) + trj[4];
        float s5 = __shfl(alpha, base + 5, 64) + trj[5];
        float s6 = __shfl(alpha, base + 6, 64) + trj[6];
        float s7 = __shfl(alpha, base + 7, 64) + trj[7];
        float s8 = __shfl(alpha, base + 8, 64) + trj[8];
        float mx = fmaxf(fmaxf(fmaxf(s0, s1), fmaxf(s2, s3)),
                         fmaxf(fmaxf(s4, s5), fmaxf(fmaxf(s6, s7), s8)));
        float sum = __expf(s0 - mx) + __expf(s1 - mx) + __expf(s2 - mx)
                  + __expf(s3 - mx) + __expf(s4 - mx) + __expf(s5 - mx)
                  + __expf(s6 - mx) + __expf(s7 - mx) + __expf(s8 - mx);
        float nxt = mx + __logf(sum) + e1;
        if (m1) alpha = nxt;
        e1 = e2; m1 = m2;
        int t2 = (t + 2 < Tn) ? t + 2 : Tn - 1;
        e2 = em[(size_t)(t2 * Bn + b) * Ln + jj];
        m2 = mask[b * Tn + t2];
    }
    float s = (lj < Ln) ? alpha + endt[lj] : -1e30f;
    float mx = s;
    #pragma unroll
    for (int d = 16; d >= 1; d >>= 1) mx = fmaxf(mx, __shfl_xor(mx, d, 64));
    float sm = __expf(s - mx);
    #pragma unroll
    for (int d = 16; d >= 1; d >>= 1) sm += __shfl_xor(sm, d, 64);
    if (lj == 0) logZ[b] = mx + __logf(sm);
}

// ---- CRF numerator: gold-path score is a plain sum -> fully parallel over t ----
__global__ __launch_bounds__(64) void k_crf_num(
    const float* __restrict__ em, const int* __restrict__ labels,
    const int* __restrict__ mask, const float* __restrict__ trans,
    const float* __restrict__ start, const float* __restrict__ endt,
    float* __restrict__ score) {
    int b = blockIdx.x, lane = threadIdx.x;
    float acc = 0.f; int cnt = 0;
    for (int t = lane; t < Tn; t += 64) {
        int tag = labels[b * Tn + t];
        int mt = mask[b * Tn + t];
        cnt += mt;
        float e = em[(size_t)(t * Bn + b) * Ln + tag];
        if (t == 0) {
            acc += start[tag] + e;
        } else {
            int prev = labels[b * Tn + t - 1];
            if (mt) acc += trans[prev * Ln + tag] + e;
        }
    }
    #pragma unroll
    for (int m = 32; m >= 1; m >>= 1) {
        acc += __shfl_xor(acc, m, 64);
        cnt += __shfl_xor(cnt, m, 64);
    }
    if (lane == 0) {
        int send = cnt - 1;
        int last = labels[b * Tn + send];
        score[b] = acc + endt[last];
    }
}

__global__ __launch_bounds__(128) void k_final(
    const float* __restrict__ score, const float* __restrict__ logZ,
    float* __restrict__ out) {
    __shared__ float s_s[128];
    int tid = threadIdx.x;
    s_s[tid] = score[tid] - logZ[tid];
    #pragma unroll
    for (int m = 64; m >= 1; m >>= 1) {
        __syncthreads();
        if (tid < m) s_s[tid] += s_s[tid + m];
    }
    if (tid == 0) out[0] = -s_s[0] / (float)Bn;
}

extern "C" void kernel_launch(void* const* d_in, const int* in_sizes, int n_in,
                              void* d_out, int out_size, void* d_ws, size_t ws_size,
                              hipStream_t stream) {
    const int* ids = (const int*)d_in[0];
    const int* msk = (const int*)d_in[1];
    const int* lbl = (const int*)d_in[2];
    const float* emb = (const float*)d_in[3];
    const float* Wih_f = (const float*)d_in[4];
    const float* Whh_f = (const float*)d_in[5];
    const float* b_f = (const float*)d_in[6];
    const float* Wih_b = (const float*)d_in[7];
    const float* Whh_b = (const float*)d_in[8];
    const float* b_b = (const float*)d_in[9];
    const float* Wc = (const float*)d_in[10];
    const float* bc = (const float*)d_in[11];
    const float* trans = (const float*)d_in[12];
    const float* st = (const float*)d_in[13];
    const float* en = (const float*)d_in[14];

    char* ws = (char*)d_ws;
    unsigned int* WT16_f = (unsigned int*)ws;   ws += (size_t)E2n * Gn * 4;     // 614,400
    unsigned int* WT16_b = (unsigned int*)ws;   ws += (size_t)E2n * Gn * 4;
    unsigned int* qr_f = (unsigned int*)ws;     ws += 98304;                    // 24 dw/thread
    unsigned int* ql_f = (unsigned int*)ws;     ws += 32768;                    // 8 dw/thread
    unsigned int* qr_b = (unsigned int*)ws;     ws += 98304;
    unsigned int* ql_b = (unsigned int*)ws;     ws += 32768;
    float* scl_f = (float*)ws;                  ws += 4096;
    float* scl_b = (float*)ws;                  ws += 4096;
    unsigned short* Pf = (unsigned short*)ws;   ws += (size_t)Vn * Gn * 2;      // 20,480,000
    unsigned short* Pb = (unsigned short*)ws;   ws += (size_t)Vn * Gn * 2;
    unsigned short* hs_f = (unsigned short*)ws; ws += (size_t)Tn * Bn * Hn * 2; // 33,554,432
    unsigned short* hs_b = (unsigned short*)ws; ws += (size_t)Tn * Bn * Hn * 2;
    float* em = (float*)ws;                     ws += (size_t)Tn * Bn * Ln * 4; // 2,359,296
    float* score = (float*)ws;                  ws += 512;
    float* logZ = (float*)ws;                   ws += 512;
    // embp (6 MB) aliases hs_f: written by k_prep_emb, read by k_proj, dead
    // before k_lstm overwrites hs_f. Re-generated every graph replay.
    unsigned int* embp = (unsigned int*)hs_f;

    k_prep_emb<<<(Vn * E2n + 255) / 256, 256, 0, stream>>>(emb, embp);
    k_prep_wt<<<dim3((E2n * Gn) / 256, 2), 256, 0, stream>>>(Wih_f, Wih_b, WT16_f, WT16_b);
    k_quant_whh<<<dim3(1024, 2), 64, 0, stream>>>(Whh_f, Whh_b, qr_f, ql_f, qr_b, ql_b, scl_f, scl_b);
    k_proj<<<dim3(313, 4, 2), 256, 0, stream>>>(embp, WT16_f, WT16_b, b_f, b_b, Pf, Pb);
    k_lstm<<<256, 1024, 0, stream>>>(ids,
        (const uint4*)qr_f, (const uint4*)ql_f, (const uint4*)qr_b, (const uint4*)ql_b,
        scl_f, scl_b, Pf, Pb, hs_f, hs_b);
    k_emit<<<16384, 256, 0, stream>>>(hs_f, hs_b, Wc, bc, em);
    k_crf_den<<<64, 64, 0, stream>>>(em, msk, trans, st, en, logZ);
    k_crf_num<<<128, 64, 0, stream>>>(em, lbl, msk, trans, st, en, score);
    k_final<<<1, 128, 0, stream>>>(score, logZ, (float*)d_out);
}

// Round 12
// 908.338 us; speedup vs baseline: 1.2498x; 1.2498x over previous
//
#include <hip/hip_runtime.h>
#include <hip/hip_bf16.h>
#include <hip/hip_fp16.h>

#define Vn 10000
#define En 300
#define E2n 150   // En/2 f16 pairs
#define Hn 256
#define Gn 1024   // 4*H
#define Ln 9
#define Bn 128
#define Tn 512

#if defined(__has_builtin)
#  if __has_builtin(__builtin_amdgcn_sdot8)
#    define HAS_SDOT8 1
#  endif
#endif
#ifndef HAS_SDOT8
#  define HAS_SDOT8 0
#endif

typedef _Float16 half2_t __attribute__((ext_vector_type(2)));

static __device__ __forceinline__ float bf2f(unsigned short u) {
    return __uint_as_float(((unsigned int)u) << 16);
}
static __device__ __forceinline__ unsigned short f2bf(float f) {
    unsigned int x = __float_as_uint(f);
    return (unsigned short)((x + 0x7FFFu + ((x >> 16) & 1u)) >> 16);
}
static __device__ __forceinline__ float sigm(float x) {
    return 1.f / (1.f + __expf(-x));
}
static __device__ __forceinline__ float tanh_fast(float x) {
    return 2.f / (1.f + __expf(-2.f * x)) - 1.f;
}
// i4x8 dot: both operands are 8 packed signed nibbles
static __device__ __forceinline__ int dot8(unsigned int w, int h, int acc) {
#if HAS_SDOT8
    return __builtin_amdgcn_sdot8((int)w, h, acc, false);
#else
    unsigned int wl = ((w & 0x0F0F0F0Fu) ^ 0x08080808u) - 0x08080808u;
    unsigned int wh = (((w >> 4) & 0x0F0F0F0Fu) ^ 0x08080808u) - 0x08080808u;
    unsigned int hl = (((unsigned)h & 0x0F0F0F0Fu) ^ 0x08080808u) - 0x08080808u;
    unsigned int hh = ((((unsigned)h >> 4) & 0x0F0F0F0Fu) ^ 0x08080808u) - 0x08080808u;
    acc = __builtin_amdgcn_sdot4((int)wl, (int)hl, acc, false);
    return __builtin_amdgcn_sdot4((int)wh, (int)hh, acc, false);
#endif
}
static __device__ __forceinline__ unsigned int packf16(float a, float b) {
    half2_t v = {(_Float16)a, (_Float16)b};
    return __builtin_bit_cast(unsigned int, v);
}
static __device__ __forceinline__ half2_t h2(unsigned int u) {
    return __builtin_bit_cast(half2_t, u);
}

#define NPREP_A 5860   // emb pack blocks
#define NPREP_B 1200   // wt pack blocks
#define NPREP_C 512    // quant blocks (4 rows each)

// ---- fused prep: emb->f16 pack | Wih->f16 transpose pack | Whh->i4 quant ----
__global__ __launch_bounds__(256) void k_prep(
    const float* __restrict__ emb, unsigned int* __restrict__ embp,
    const float* __restrict__ Wih_f, const float* __restrict__ Wih_b,
    unsigned int* __restrict__ WT16_f, unsigned int* __restrict__ WT16_b,
    const float* __restrict__ Whh_f, const float* __restrict__ Whh_b,
    unsigned int* __restrict__ qr_f, unsigned int* __restrict__ ql_f,
    unsigned int* __restrict__ qr_b, unsigned int* __restrict__ ql_b,
    float* __restrict__ scl_f, float* __restrict__ scl_b) {
    int bx = blockIdx.x, tid = threadIdx.x;
    if (bx < NPREP_A) {                                  // emb pack
        int n = bx * 256 + tid;
        if (n < Vn * E2n) {
            int v = n / E2n, e2 = n % E2n;
            embp[n] = packf16(emb[(size_t)v * En + 2 * e2],
                              emb[(size_t)v * En + 2 * e2 + 1]);
        }
        return;
    }
    if (bx < NPREP_A + NPREP_B) {                        // Wih transpose pack
        int m = (bx - NPREP_A) * 256 + tid;              // < 307200
        int dir = m / 153600;
        int n = m % 153600;
        const float* src = dir ? Wih_b : Wih_f;
        unsigned int* dst = dir ? WT16_b : WT16_f;
        int e2 = n / Gn, j = n % Gn;
        dst[n] = packf16(src[(size_t)j * En + 2 * e2],
                         src[(size_t)j * En + 2 * e2 + 1]);
        return;
    }
    // Whh quant: 4 gate-rows per block, one wave each. r10 layout:
    // dwords e=0..23 -> qr tiles [e>>2][1024]; e=24..31 -> ql tiles.
    int idx = (bx - NPREP_A - NPREP_B) * 4 + (tid >> 6); // < 2048
    int dir = idx >> 10;
    int j = idx & 1023;
    int lane = tid & 63;
    const float* W = dir ? Whh_b : Whh_f;
    float w8[8];
    float m = 0.f;
    if (lane < 32) {
        float4 wlo = *(const float4*)&W[(size_t)j * Hn + 8 * lane];
        float4 whi = *(const float4*)&W[(size_t)j * Hn + 8 * lane + 4];
        w8[0] = wlo.x; w8[1] = wlo.y; w8[2] = wlo.z; w8[3] = wlo.w;
        w8[4] = whi.x; w8[5] = whi.y; w8[6] = whi.z; w8[7] = whi.w;
        #pragma unroll
        for (int i = 0; i < 8; ++i) m = fmaxf(m, fabsf(w8[i]));
    }
    #pragma unroll
    for (int sft = 32; sft >= 1; sft >>= 1) m = fmaxf(m, __shfl_xor(m, sft, 64));
    float inv = (m > 0.f) ? (7.f / m) : 0.f;
    if (lane < 32) {
        unsigned int d = 0;
        #pragma unroll
        for (int i = 0; i < 8; ++i) {
            int qi = (int)rintf(w8[i] * inv);
            d |= ((unsigned int)(qi & 0xF)) << (4 * i);
        }
        if (lane < 24)
            (dir ? qr_b : qr_f)[(size_t)((lane >> 2) * 1024 + j) * 4 + (lane & 3)] = d;
        else {
            int e = lane - 24;
            (dir ? ql_b : ql_f)[(size_t)((e >> 2) * 1024 + j) * 4 + (e & 3)] = d;
        }
    }
    if (lane == 0) (dir ? scl_b : scl_f)[j] = m / 49.f;
}

// ---- P = emb @ WihT + b via v_pk_fma_f16 : (10000, 1024) bf16 per dir ----
// half2 accumulators: clang lowers _Float16 vector FMA to v_pk_fma_f16
// (2 MAC/inst) — no builtin-availability gamble (the r9 fdot2 lesson).
__global__ __launch_bounds__(256) void k_proj(
    const unsigned int* __restrict__ embp,
    const unsigned int* __restrict__ WT16_f, const unsigned int* __restrict__ WT16_b,
    const float* __restrict__ b_f, const float* __restrict__ b_b,
    unsigned short* __restrict__ Pf, unsigned short* __restrict__ Pb) {
    int tid = threadIdx.x;
    int tx = tid & 63, ty = tid >> 6;
    int dir = blockIdx.z;
    const unsigned int* WT = dir ? WT16_b : WT16_f;
    const float* bias = dir ? b_b : b_f;
    unsigned short* P = dir ? Pb : Pf;
    int v0 = blockIdx.x * 32 + ty * 8;               // 313 blocks, tail-guarded
    int j0 = blockIdx.y * 256 + tx * 4;
    int vr[8];
    #pragma unroll
    for (int r = 0; r < 8; ++r) { int v = v0 + r; vr[r] = (v < Vn) ? v : Vn - 1; }
    half2_t ax[8], ay[8], az[8], aw[8];
    #pragma unroll
    for (int r = 0; r < 8; ++r) {
        half2_t z = {(_Float16)0.f, (_Float16)0.f};
        ax[r] = z; ay[r] = z; az[r] = z; aw[r] = z;
    }
    for (int e2 = 0; e2 < E2n; e2 += 2) {            // 150 even
        uint4 w0 = *(const uint4*)&WT[(size_t)(e2 + 0) * Gn + j0];
        uint4 w1 = *(const uint4*)&WT[(size_t)(e2 + 1) * Gn + j0];
        #pragma unroll
        for (int r = 0; r < 8; ++r) {
            uint2 a = *(const uint2*)&embp[(size_t)vr[r] * E2n + e2];
            half2_t a0 = h2(a.x), a1 = h2(a.y);
            ax[r] += a0 * h2(w0.x); ay[r] += a0 * h2(w0.y);
            az[r] += a0 * h2(w0.z); aw[r] += a0 * h2(w0.w);
            ax[r] += a1 * h2(w1.x); ay[r] += a1 * h2(w1.y);
            az[r] += a1 * h2(w1.z); aw[r] += a1 * h2(w1.w);
        }
    }
    float4 bb = *(const float4*)&bias[j0];
    #pragma unroll
    for (int r = 0; r < 8; ++r) {
        if (v0 + r < Vn) {
            ushort4 o;
            o.x = f2bf((float)ax[r].x + (float)ax[r].y + bb.x);
            o.y = f2bf((float)ay[r].x + (float)ay[r].y + bb.y);
            o.z = f2bf((float)az[r].x + (float)az[r].y + bb.z);
            o.w = f2bf((float)aw[r].x + (float)aw[r].y + bb.w);
            *(ushort4*)&P[(size_t)(v0 + r) * Gn + j0] = o;
        }
    }
}

// ---- persistent BiLSTM recurrence: 256 WGs = 2 dir x 128 batch, 1024 thr ----
// r10 core verbatim (best measured): 24 i4-dwords pinned + 8 in LDS,
// 1 h ds_read_b128 + readlane -> dot8, 4 accumulator chains, 2 barriers.
__global__ __launch_bounds__(1024, 4) void k_lstm(
    const int* __restrict__ ids,
    const uint4* __restrict__ qr_f, const uint4* __restrict__ ql_f,
    const uint4* __restrict__ qr_b, const uint4* __restrict__ ql_b,
    const float* __restrict__ scl_f, const float* __restrict__ scl_b,
    const unsigned short* __restrict__ Pf, const unsigned short* __restrict__ Pb,
    unsigned short* __restrict__ hs_f, unsigned short* __restrict__ hs_b) {
    __shared__ uint4 wlds[2 * 1024];         // 32 KB streamed weight half (k=192..255)
    __shared__ float g_stage[Gn];            // 4 KB gate preacts
    __shared__ uint4 h4v[8];                 // 128 B i4 h (dword D = units 8D..8D+7)
    __shared__ int ids_lds[Tn];              // 2 KB
    int tid = threadIdx.x;
    int dir = blockIdx.x >> 7;
    int batch = blockIdx.x & 127;
    const uint4* qr = dir ? qr_b : qr_f;
    const uint4* ql = dir ? ql_b : ql_f;
    const unsigned short* P = dir ? Pb : Pf;
    unsigned short* hs = dir ? hs_b : hs_f;

    unsigned int wReg[24];
    #pragma unroll
    for (int d4 = 0; d4 < 6; ++d4) {
        uint4 v = qr[(size_t)d4 * 1024 + tid];
        wReg[4*d4+0] = v.x; wReg[4*d4+1] = v.y; wReg[4*d4+2] = v.z; wReg[4*d4+3] = v.w;
    }
    wlds[tid] = ql[tid];
    wlds[1024 + tid] = ql[1024 + tid];
    float sc = (dir ? scl_b : scl_f)[tid];
    if (tid < Tn) ids_lds[tid] = ids[batch * Tn + tid];
    if (tid < 8) { uint4 z = {0u, 0u, 0u, 0u}; h4v[tid] = z; }
    float c = 0.f;
    __syncthreads();

    int t0 = dir ? (Tn - 1) : 0;
    float p = bf2f(P[(size_t)ids_lds[t0] * Gn + tid]);

    for (int s = 0; s < Tn; ++s) {
        // loop-carried pin: wReg must be live in VGPRs/AGPRs each iteration
        asm volatile("" : "+v"(wReg[0]), "+v"(wReg[1]), "+v"(wReg[2]), "+v"(wReg[3]),
                          "+v"(wReg[4]), "+v"(wReg[5]), "+v"(wReg[6]), "+v"(wReg[7]),
                          "+v"(wReg[8]), "+v"(wReg[9]), "+v"(wReg[10]), "+v"(wReg[11]));
        asm volatile("" : "+v"(wReg[12]), "+v"(wReg[13]), "+v"(wReg[14]), "+v"(wReg[15]),
                          "+v"(wReg[16]), "+v"(wReg[17]), "+v"(wReg[18]), "+v"(wReg[19]),
                          "+v"(wReg[20]), "+v"(wReg[21]), "+v"(wReg[22]), "+v"(wReg[23]));

        int t = dir ? (Tn - 1 - s) : s;
        int s2 = (s + 1 < Tn) ? s + 1 : Tn - 1;
        int t2 = dir ? (Tn - 1 - s2) : s2;
        unsigned short nx = P[(size_t)ids_lds[t2] * Gn + tid];   // next-step prefetch

        uint4 hq  = h4v[tid & 7];                     // 1 ds_read_b128
        uint4 wv0 = wlds[tid];                        // 2 ds_read_b128 (k=192..255)
        uint4 wv1 = wlds[1024 + tid];

        int a0 = 0, a1 = 0, a2 = 0, a3 = 0;           // 4 independent chains
        #pragma unroll
        for (int g = 0; g < 6; ++g) {                 // register half: h dwords 0..23
            int h0 = __builtin_amdgcn_readlane((int)hq.x, g);
            int h1 = __builtin_amdgcn_readlane((int)hq.y, g);
            int h2v = __builtin_amdgcn_readlane((int)hq.z, g);
            int h3 = __builtin_amdgcn_readlane((int)hq.w, g);
            a0 = dot8(wReg[4*g+0], h0, a0);
            a1 = dot8(wReg[4*g+1], h1, a1);
            a2 = dot8(wReg[4*g+2], h2v, a2);
            a3 = dot8(wReg[4*g+3], h3, a3);
        }
        {                                             // LDS half: h dwords 24..31
            int h0 = __builtin_amdgcn_readlane((int)hq.x, 6);
            int h1 = __builtin_amdgcn_readlane((int)hq.y, 6);
            int h2v = __builtin_amdgcn_readlane((int)hq.z, 6);
            int h3 = __builtin_amdgcn_readlane((int)hq.w, 6);
            a0 = dot8(wv0.x, h0, a0);
            a1 = dot8(wv0.y, h1, a1);
            a2 = dot8(wv0.z, h2v, a2);
            a3 = dot8(wv0.w, h3, a3);
            h0 = __builtin_amdgcn_readlane((int)hq.x, 7);
            h1 = __builtin_amdgcn_readlane((int)hq.y, 7);
            h2v = __builtin_amdgcn_readlane((int)hq.z, 7);
            h3 = __builtin_amdgcn_readlane((int)hq.w, 7);
            a0 = dot8(wv1.x, h0, a0);
            a1 = dot8(wv1.y, h1, a1);
            a2 = dot8(wv1.z, h2v, a2);
            a3 = dot8(wv1.w, h3, a3);
        }
        g_stage[tid] = sc * (float)((a0 + a1) + (a2 + a3)) + p;
        __syncthreads();                              // B1: gates ready
        if (tid < Hn) {
            float gi = g_stage[tid];
            float gf = g_stage[tid + 256];
            float gg = g_stage[tid + 512];
            float go = g_stage[tid + 768];
            float cn = sigm(gf) * c + sigm(gi) * tanh_fast(gg);
            float hn = sigm(go) * tanh_fast(cn);
            c = cn;
            hs[(size_t)(t * Bn + batch) * Hn + tid] = f2bf(hn);
            int qh = (int)rintf(7.f * hn);            // in [-7,7]
            int qo = __shfl_xor(qh, 1, 64);           // partner unit, same wave
            if ((tid & 1) == 0)
                ((char*)h4v)[tid >> 1] = (char)((qh & 0xF) | ((qo & 0xF) << 4));
        }
        __syncthreads();                              // B2: new h visible
        p = bf2f(nx);
    }
}

// ---- emissions: 16 tokens per block (4 waves x 4), Wc staged once ----
__global__ __launch_bounds__(256) void k_emit(
    const unsigned short* __restrict__ hs_f, const unsigned short* __restrict__ hs_b,
    const float* __restrict__ Wc, const float* __restrict__ bc,
    float* __restrict__ em) {
    __shared__ float wc_s[Ln * 2 * Hn];
    int tid = threadIdx.x;
    for (int i = tid; i < Ln * 2 * Hn; i += 256) wc_s[i] = Wc[i];
    __syncthreads();
    int lane = tid & 63, wid = tid >> 6;
    int tb0 = blockIdx.x * 16 + wid * 4;             // 4096 blocks x 16 tokens
    for (int i = 0; i < 4; ++i) {
        int tb = tb0 + i;                            // t*128 + b, < 65536
        const unsigned short* hf = hs_f + (size_t)tb * Hn;
        const unsigned short* hb = hs_b + (size_t)tb * Hn;
        uint2 uf = *(const uint2*)&hf[lane * 4];
        uint2 ub = *(const uint2*)&hb[lane * 4];
        float f0 = __uint_as_float(uf.x << 16), f1 = __uint_as_float(uf.x & 0xFFFF0000u);
        float f2v = __uint_as_float(uf.y << 16), f3 = __uint_as_float(uf.y & 0xFFFF0000u);
        float b0 = __uint_as_float(ub.x << 16), b1 = __uint_as_float(ub.x & 0xFFFF0000u);
        float b2 = __uint_as_float(ub.y << 16), b3 = __uint_as_float(ub.y & 0xFFFF0000u);
        #pragma unroll
        for (int l = 0; l < Ln; ++l) {
            const float* w = &wc_s[l * 2 * Hn];
            float pe = f0 * w[4 * lane] + f1 * w[4 * lane + 1]
                     + f2v * w[4 * lane + 2] + f3 * w[4 * lane + 3]
                     + b0 * w[Hn + 4 * lane] + b1 * w[Hn + 4 * lane + 1]
                     + b2 * w[Hn + 4 * lane + 2] + b3 * w[Hn + 4 * lane + 3];
            #pragma unroll
            for (int m = 32; m >= 1; m >>= 1) pe += __shfl_xor(pe, m, 64);
            if (lane == 0) em[(size_t)tb * Ln + l] = pe + bc[l];
        }
    }
}

// ---- CRF den+num, fused at BLOCK level (independent WGs, co-resident):
// blocks 0..63: den for batches {bx, bx+64} (2/wave); blocks 64..191: num. ----
__global__ __launch_bounds__(64) void k_crf(
    const float* __restrict__ em, const int* __restrict__ labels,
    const int* __restrict__ mask, const float* __restrict__ trans,
    const float* __restrict__ start, const float* __restrict__ endt,
    float* __restrict__ score, float* __restrict__ logZ) {
    int lane = threadIdx.x;
    if (blockIdx.x >= 64) {                          // ---- numerator ----
        int b = blockIdx.x - 64;
        float acc = 0.f; int cnt = 0;
        for (int t = lane; t < Tn; t += 64) {
            int tag = labels[b * Tn + t];
            int mt = mask[b * Tn + t];
            cnt += mt;
            float e = em[(size_t)(t * Bn + b) * Ln + tag];
            if (t == 0) {
                acc += start[tag] + e;
            } else {
                int prev = labels[b * Tn + t - 1];
                if (mt) acc += trans[prev * Ln + tag] + e;
            }
        }
        #pragma unroll
        for (int m = 32; m >= 1; m >>= 1) {
            acc += __shfl_xor(acc, m, 64);
            cnt += __shfl_xor(cnt, m, 64);
        }
        if (lane == 0) {
            int send = cnt - 1;
            int last = labels[b * Tn + send];
            score[b] = acc + endt[last];
        }
        return;
    }
    // ---- denominator: 2 batches/wave (lanes 0-8 / 32-40) ----
    int grp = lane >> 5;
    int b = blockIdx.x + 64 * grp;
    int lj = lane & 31;
    int jj = (lj < Ln) ? lj : Ln - 1;
    int base = lane & 32;
    float trj[Ln];
    #pragma unroll
    for (int i = 0; i < Ln; ++i) trj[i] = trans[i * Ln + jj];
    float alpha = start[jj] + em[(size_t)b * Ln + jj];
    float e1 = em[(size_t)(1 * Bn + b) * Ln + jj];
    float e2 = em[(size_t)(2 * Bn + b) * Ln + jj];
    int m1 = mask[b * Tn + 1];
    int m2 = mask[b * Tn + 2];
    for (int t = 1; t < Tn; ++t) {
        float s0 = __shfl(alpha, base + 0, 64) + trj[0];
        float s1 = __shfl(alpha, base + 1, 64) + trj[1];
        float s2 = __shfl(alpha, base + 2, 64) + trj[2];
        float s3 = __shfl(alpha, base + 3, 64) + trj[3];
        float s4 = __shfl(alpha, base + 4, 64) + trj[4];
        float s5 = __shfl(alpha, base + 5, 64) + trj[5];
        float s6 = __shfl(alpha, base + 6, 64) + trj[6];
        float s7 = __shfl(alpha, base + 7, 64) + trj[7];
        float s8 = __shfl(alpha, base + 8, 64) + trj[8];
        float mx = fmaxf(fmaxf(fmaxf(s0, s1), fmaxf(s2, s3)),
                         fmaxf(fmaxf(s4, s5), fmaxf(fmaxf(s6, s7), s8)));
        float sum = __expf(s0 - mx) + __expf(s1 - mx) + __expf(s2 - mx)
                  + __expf(s3 - mx) + __expf(s4 - mx) + __expf(s5 - mx)
                  + __expf(s6 - mx) + __expf(s7 - mx) + __expf(s8 - mx);
        float nxt = mx + __logf(sum) + e1;
        if (m1) alpha = nxt;
        e1 = e2; m1 = m2;
        int t2 = (t + 2 < Tn) ? t + 2 : Tn - 1;
        e2 = em[(size_t)(t2 * Bn + b) * Ln + jj];
        m2 = mask[b * Tn + t2];
    }
    float s = (lj < Ln) ? alpha + endt[lj] : -1e30f;
    float mx = s;
    #pragma unroll
    for (int d = 16; d >= 1; d >>= 1) mx = fmaxf(mx, __shfl_xor(mx, d, 64));
    float sm = __expf(s - mx);
    #pragma unroll
    for (int d = 16; d >= 1; d >>= 1) sm += __shfl_xor(sm, d, 64);
    if (lj == 0) logZ[b] = mx + __logf(sm);
}

__global__ __launch_bounds__(128) void k_final(
    const float* __restrict__ score, const float* __restrict__ logZ,
    float* __restrict__ out) {
    __shared__ float s_s[128];
    int tid = threadIdx.x;
    s_s[tid] = score[tid] - logZ[tid];
    #pragma unroll
    for (int m = 64; m >= 1; m >>= 1) {
        __syncthreads();
        if (tid < m) s_s[tid] += s_s[tid + m];
    }
    if (tid == 0) out[0] = -s_s[0] / (float)Bn;
}

extern "C" void kernel_launch(void* const* d_in, const int* in_sizes, int n_in,
                              void* d_out, int out_size, void* d_ws, size_t ws_size,
                              hipStream_t stream) {
    const int* ids = (const int*)d_in[0];
    const int* msk = (const int*)d_in[1];
    const int* lbl = (const int*)d_in[2];
    const float* emb = (const float*)d_in[3];
    const float* Wih_f = (const float*)d_in[4];
    const float* Whh_f = (const float*)d_in[5];
    const float* b_f = (const float*)d_in[6];
    const float* Wih_b = (const float*)d_in[7];
    const float* Whh_b = (const float*)d_in[8];
    const float* b_b = (const float*)d_in[9];
    const float* Wc = (const float*)d_in[10];
    const float* bc = (const float*)d_in[11];
    const float* trans = (const float*)d_in[12];
    const float* st = (const float*)d_in[13];
    const float* en = (const float*)d_in[14];

    char* ws = (char*)d_ws;
    unsigned int* WT16_f = (unsigned int*)ws;   ws += (size_t)E2n * Gn * 4;     // 614,400
    unsigned int* WT16_b = (unsigned int*)ws;   ws += (size_t)E2n * Gn * 4;
    unsigned int* qr_f = (unsigned int*)ws;     ws += 98304;                    // 24 dw/row
    unsigned int* ql_f = (unsigned int*)ws;     ws += 32768;                    // 8 dw/row
    unsigned int* qr_b = (unsigned int*)ws;     ws += 98304;
    unsigned int* ql_b = (unsigned int*)ws;     ws += 32768;
    float* scl_f = (float*)ws;                  ws += 4096;
    float* scl_b = (float*)ws;                  ws += 4096;
    unsigned short* Pf = (unsigned short*)ws;   ws += (size_t)Vn * Gn * 2;      // 20,480,000
    unsigned short* Pb = (unsigned short*)ws;   ws += (size_t)Vn * Gn * 2;
    unsigned short* hs_f = (unsigned short*)ws; ws += (size_t)Tn * Bn * Hn * 2; // 33,554,432
    unsigned short* hs_b = (unsigned short*)ws; ws += (size_t)Tn * Bn * Hn * 2;
    float* em = (float*)ws;                     ws += (size_t)Tn * Bn * Ln * 4; // 2,359,296
    float* score = (float*)ws;                  ws += 512;
    float* logZ = (float*)ws;                   ws += 512;
    // embp (6 MB) aliases hs_f: written by k_prep, read by k_proj, dead
    // before k_lstm overwrites hs_f. Re-generated every graph replay.
    unsigned int* embp = (unsigned int*)hs_f;

    k_prep<<<NPREP_A + NPREP_B + NPREP_C, 256, 0, stream>>>(
        emb, embp, Wih_f, Wih_b, WT16_f, WT16_b,
        Whh_f, Whh_b, qr_f, ql_f, qr_b, ql_b, scl_f, scl_b);
    k_proj<<<dim3(313, 4, 2), 256, 0, stream>>>(embp, WT16_f, WT16_b, b_f, b_b, Pf, Pb);
    k_lstm<<<256, 1024, 0, stream>>>(ids,
        (const uint4*)qr_f, (const uint4*)ql_f, (const uint4*)qr_b, (const uint4*)ql_b,
        scl_f, scl_b, Pf, Pb, hs_f, hs_b);
    k_emit<<<4096, 256, 0, stream>>>(hs_f, hs_b, Wc, bc, em);
    k_crf<<<192, 64, 0, stream>>>(em, lbl, msk, trans, st, en, score, logZ);
    k_final<<<1, 128, 0, stream>>>(score, logZ, (float*)d_out);
}